// Round 1
// baseline (596.200 us; speedup 1.0000x reference)
//
#include <hip/hip_runtime.h>
#include <hip/hip_bf16.h>
#include <stdint.h>

// Problem constants
#define S_LEN 1024
#define B_SZ  64
#define I_SZ  512
#define H_SZ  2048
#define O_SZ  512
#define BH    (B_SZ * H_SZ)      // 131072

typedef __bf16  bf16x8 __attribute__((ext_vector_type(8)));
typedef float   f32x4  __attribute__((ext_vector_type(4)));

static __device__ __forceinline__ ushort f2bf(float f) {
  union { float f; unsigned u; } v; v.f = f;
  unsigned r = v.u + 0x7FFFu + ((v.u >> 16) & 1u);   // RNE
  return (ushort)(r >> 16);
}

// async global->LDS, 16B per lane, wave-uniform LDS base + lane*16
#define GLOAD_LDS16(gp, lp) \
  __builtin_amdgcn_global_load_lds( \
      (__attribute__((address_space(1))) void*)(gp), \
      (__attribute__((address_space(3))) void*)(lp), 16, 0, 0)

// ---------------------------------------------------------------- converts
__global__ __launch_bounds__(256) void convert_f32_bf16_kernel(
    const float4* __restrict__ in, ushort4* __restrict__ out, int n4) {
  int i = blockIdx.x * 256 + threadIdx.x;
  if (i >= n4) return;
  float4 v = in[i];
  ushort4 o; o.x = f2bf(v.x); o.y = f2bf(v.y); o.z = f2bf(v.z); o.w = f2bf(v.w);
  out[i] = o;
}

// ---------------------------------------------------------------- GEMM u = Xbf @ Wbf^T
// A: [M][512] bf16 row-major (K contiguous), B: [2048][512] bf16 (B^T layout),
// U: [M][2048] fp32 (or bf16 if UBF). 128x128 block tile, 4 waves of 64x64,
// 16x16x32 bf16 MFMA, BK=64, global_load_lds staging.
template<int UBF>
__global__ __launch_bounds__(256, 2) void gemm_u_kernel(
    const ushort* __restrict__ A, const ushort* __restrict__ Bm,
    void* __restrict__ Uout, int M) {
  __shared__ __align__(16) ushort As[128 * 64];
  __shared__ __align__(16) ushort Bs[128 * 64];
  const int tid  = threadIdx.x;
  const int wave = tid >> 6;
  const int lane = tid & 63;
  const int bn = blockIdx.x;            // N/128 = 16
  const int bm = blockIdx.y;            // M/128
  const int wm = (wave >> 1) * 64;
  const int wn = (wave & 1) * 64;
  const int ml = lane & 15;
  const int q  = lane >> 4;

  f32x4 acc[4][4] = {};

  // staging: each wave stages 32 rows of A and 32 rows of B per k-iter
  const int r0   = wave * 32;
  const int srow = lane >> 3;           // 0..7
  const int scol = (lane & 7) * 8;      // bf16 col within 64
  const ushort* gA = A  + (size_t)(bm * 128 + r0 + srow) * I_SZ + scol;
  const ushort* gB = Bm + (size_t)(bn * 128 + r0 + srow) * I_SZ + scol;
  ushort* lA = &As[r0 * 64];
  ushort* lB = &Bs[r0 * 64];

  for (int kt = 0; kt < I_SZ / 64; ++kt) {
    __syncthreads();
    #pragma unroll
    for (int j = 0; j < 4; ++j) {
      GLOAD_LDS16(gA + (size_t)(j * 8) * I_SZ + kt * 64, lA + j * 8 * 64);
      GLOAD_LDS16(gB + (size_t)(j * 8) * I_SZ + kt * 64, lB + j * 8 * 64);
    }
    __syncthreads();
    #pragma unroll
    for (int ks = 0; ks < 2; ++ks) {
      bf16x8 af[4], bf[4];
      #pragma unroll
      for (int i = 0; i < 4; ++i) {
        af[i] = *(const bf16x8*)&As[(wm + i * 16 + ml) * 64 + ks * 32 + q * 8];
        bf[i] = *(const bf16x8*)&Bs[(wn + i * 16 + ml) * 64 + ks * 32 + q * 8];
      }
      #pragma unroll
      for (int mi = 0; mi < 4; ++mi)
        #pragma unroll
        for (int ni = 0; ni < 4; ++ni)
          acc[mi][ni] = __builtin_amdgcn_mfma_f32_16x16x32_bf16(
              af[mi], bf[ni], acc[mi][ni], 0, 0, 0);
    }
  }

  // epilogue: C/D layout col=lane&15, row=(lane>>4)*4+reg
  const int rowb = bm * 128 + wm + q * 4;
  const int colb = bn * 128 + wn + ml;
  #pragma unroll
  for (int mi = 0; mi < 4; ++mi) {
    #pragma unroll
    for (int ni = 0; ni < 4; ++ni) {
      #pragma unroll
      for (int r = 0; r < 4; ++r) {
        size_t idx = (size_t)(rowb + mi * 16 + r) * H_SZ + (colb + ni * 16);
        if (UBF) ((ushort*)Uout)[idx] = f2bf(acc[mi][ni][r]);
        else     ((float*) Uout)[idx] = acc[mi][ni][r];
      }
    }
  }
}

// ---------------------------------------------------------------- scan
// u layout: [s][b][h] with (b*2048+h) = idx; one thread per (b,h) chain.
template<int UBF>
__global__ __launch_bounds__(256) void scan_kernel(
    const void* __restrict__ Uv, const float* __restrict__ hh,
    float* __restrict__ hstate, int steps, int first) {
  int idx = blockIdx.x * 256 + threadIdx.x;       // 0..131071
  float c  = hh[idx & (H_SZ - 1)];
  float hs = first ? 0.0f : hstate[idx];
  if (UBF) {
    const ushort* U = (const ushort*)Uv + idx;
    #pragma unroll 8
    for (int s = 0; s < steps; ++s) {
      unsigned uu = (unsigned)U[(size_t)s * BH] << 16;
      float uf = __builtin_bit_cast(float, uu);
      hs = fabsf(uf + c * hs);
    }
  } else {
    const float* U = (const float*)Uv + idx;
    #pragma unroll 8
    for (int s = 0; s < steps; ++s) {
      hs = fabsf(U[(size_t)s * BH] + c * hs);
    }
  }
  hstate[idx] = hs;
}

// ---------------------------------------------------------------- final Y = h @ W_ho^T + b
// one wave per output element (b,o); coalesced float4 reads over k.
__global__ __launch_bounds__(256) void final_kernel(
    const float* __restrict__ hstate, const float* __restrict__ Who,
    const float* __restrict__ bho, float* __restrict__ Y) {
  int wid  = blockIdx.x * 4 + (threadIdx.x >> 6);
  int lane = threadIdx.x & 63;
  int o = wid & (O_SZ - 1);
  int b = wid >> 9;
  const float4* hp = (const float4*)(hstate + (size_t)b * H_SZ);
  const float4* wp = (const float4*)(Who + (size_t)o * H_SZ);
  float acc = 0.0f;
  #pragma unroll
  for (int p = 0; p < 8; ++p) {
    float4 hv = hp[p * 64 + lane];
    float4 wv = wp[p * 64 + lane];
    acc += hv.x * wv.x + hv.y * wv.y + hv.z * wv.z + hv.w * wv.w;
  }
  #pragma unroll
  for (int off = 32; off; off >>= 1) acc += __shfl_down(acc, off);
  if (lane == 0) Y[(size_t)b * O_SZ + o] = acc + bho[o];
}

// ---------------------------------------------------------------- launch
extern "C" void kernel_launch(void* const* d_in, const int* in_sizes, int n_in,
                              void* d_out, int out_size, void* d_ws, size_t ws_size,
                              hipStream_t stream) {
  const float* X    = (const float*)d_in[0];   // [1024][64][512]
  const float* Wih  = (const float*)d_in[1];   // [2048][512]
  const float* hh   = (const float*)d_in[2];   // [2048]
  const float* Who  = (const float*)d_in[3];   // [512][2048]
  const float* bho  = (const float*)d_in[4];   // [512]
  float* Y = (float*)d_out;                    // [64][512]

  const size_t XBF = (size_t)S_LEN * B_SZ * I_SZ * 2;  // 64 MiB
  const size_t WBF = (size_t)H_SZ * I_SZ * 2;          // 2 MiB
  const size_t HST = (size_t)BH * 4;                   // 512 KiB
  const size_t base = XBF + WBF + HST;

  // pick chunking: smallest #chunks whose u-buffer fits ws
  int nch = 0, ubf = 0;
  {
    const int cand_f32[5] = {1, 2, 4, 8, 16};
    for (int i = 0; i < 5 && !nch; ++i) {
      size_t need = base + (size_t)(S_LEN / cand_f32[i]) * BH * 4;
      if (need <= ws_size) nch = cand_f32[i];
    }
    if (!nch) {
      const int cand_bf[3] = {16, 32, 64};
      ubf = 1;
      for (int i = 0; i < 3 && !nch; ++i) {
        size_t need = base + (size_t)(S_LEN / cand_bf[i]) * BH * 2;
        if (need <= ws_size) nch = cand_bf[i];
      }
      if (!nch) nch = 64;  // last resort
    }
  }

  char* w = (char*)d_ws;
  ushort* Xbf    = (ushort*)w;
  ushort* Wbf    = (ushort*)(w + XBF);
  float*  hstate = (float*) (w + XBF + WBF);
  void*   U      = (void*)  (w + XBF + WBF + HST);

  // converts (exact grids)
  {
    int n4x = (int)((size_t)S_LEN * B_SZ * I_SZ / 4);  // 8388608
    convert_f32_bf16_kernel<<<n4x / 256, 256, 0, stream>>>(
        (const float4*)X, (ushort4*)Xbf, n4x);
    int n4w = (int)((size_t)H_SZ * I_SZ / 4);          // 262144
    convert_f32_bf16_kernel<<<n4w / 256, 256, 0, stream>>>(
        (const float4*)Wih, (ushort4*)Wbf, n4w);
  }

  const int chunk = S_LEN / nch;          // steps per chunk (>= 16)
  const int M = chunk * B_SZ;             // GEMM rows per chunk (mult of 128)
  for (int c = 0; c < nch; ++c) {
    const ushort* Ab = Xbf + (size_t)c * chunk * B_SZ * I_SZ;
    dim3 g(H_SZ / 128, M / 128);
    if (ubf) gemm_u_kernel<1><<<g, 256, 0, stream>>>(Ab, Wbf, U, M);
    else     gemm_u_kernel<0><<<g, 256, 0, stream>>>(Ab, Wbf, U, M);
    if (ubf) scan_kernel<1><<<BH / 256, 256, 0, stream>>>(U, hh, hstate, chunk, c == 0);
    else     scan_kernel<0><<<BH / 256, 256, 0, stream>>>(U, hh, hstate, chunk, c == 0);
  }

  final_kernel<<<(B_SZ * O_SZ) / 4, 256, 0, stream>>>(hstate, Who, bho, Y);
}

// Round 2
// 453.306 us; speedup vs baseline: 1.3152x; 1.3152x over previous
//
#include <hip/hip_runtime.h>
#include <hip/hip_bf16.h>
#include <stdint.h>

// Problem constants
#define S_LEN 1024
#define B_SZ  64
#define I_SZ  512
#define H_SZ  2048
#define O_SZ  512
#define BH    (B_SZ * H_SZ)      // 131072

typedef __bf16  bf16x8 __attribute__((ext_vector_type(8)));
typedef float   f32x4  __attribute__((ext_vector_type(4)));

static __device__ __forceinline__ ushort f2bf(float f) {
  union { float f; unsigned u; } v; v.f = f;
  unsigned r = v.u + 0x7FFFu + ((v.u >> 16) & 1u);   // RNE
  return (ushort)(r >> 16);
}

// async global->LDS, 16B per lane, wave-uniform LDS base + lane*16
#define GLOAD_LDS16(gp, lp) \
  __builtin_amdgcn_global_load_lds( \
      (__attribute__((address_space(1))) void*)(gp), \
      (__attribute__((address_space(3))) void*)(lp), 16, 0, 0)

// ---------------------------------------------------------------- converts
__global__ __launch_bounds__(256) void convert_f32_bf16_kernel(
    const float4* __restrict__ in, ushort4* __restrict__ out, int n4) {
  int i = blockIdx.x * 256 + threadIdx.x;
  if (i >= n4) return;
  float4 v = in[i];
  ushort4 o; o.x = f2bf(v.x); o.y = f2bf(v.y); o.z = f2bf(v.z); o.w = f2bf(v.w);
  out[i] = o;
}

// ---------------------------------------------------------------- GEMM u = Xbf @ Wbf^T
// A: [65536][512] bf16, B: [2048][512] bf16 (B^T layout), U: [65536][2048] bf16.
// 128x128 tile, 4 waves of 64x64, 16x16x32 MFMA, BK=64.
// LDS layout swizzle: row r's 16B chunk c is stored at slot (c + r) & 7 — set up
// on the GLOBAL side of global_load_lds so fragment ds_read_b128 are conflict-free.
// XCD swizzle: 16 bn-tiles of one bm stay on one XCD's L2.
__global__ __launch_bounds__(256, 2) void gemm_u_kernel(
    const ushort* __restrict__ A, const ushort* __restrict__ Bm,
    ushort* __restrict__ U) {
  __shared__ __align__(16) ushort smem[17408];   // 34816 B: As(8192)+Bs(8192), C-tile reuse
  ushort* As = smem;
  ushort* Bs = smem + 8192;

  const int tid  = threadIdx.x;
  const int wave = tid >> 6;
  const int lane = tid & 63;

  // XCD-aware block swizzle (8192 blocks; XCD = blockIdx % 8 heuristic)
  const int b  = blockIdx.x;
  const int x  = b & 7;
  const int j  = b >> 3;               // 0..1023
  const int bn = j & 15;               // 0..15
  const int bm = ((j >> 4) << 3) | x;  // 0..511

  const int wm = (wave >> 1) * 64;
  const int wn = (wave & 1) * 64;
  const int ml = lane & 15;
  const int q  = lane >> 4;

  f32x4 acc[4][4] = {};

  // staging: wave stages 32 rows of A and B; lane -> (row = lane>>3, slot = lane&7)
  // slot s of row r holds global chunk (s - r) & 7  (rotate-by-row swizzle)
  const int r0     = wave * 32;
  const int srow   = lane >> 3;
  const int schunk = ((lane & 7) - srow) & 7;
  const ushort* gA = A  + (size_t)(bm * 128 + r0 + srow) * I_SZ + schunk * 8;
  const ushort* gB = Bm + (size_t)(bn * 128 + r0 + srow) * I_SZ + schunk * 8;
  ushort* lA = As + r0 * 64;
  ushort* lB = Bs + r0 * 64;

  // fragment read offsets: wanted chunk c = ks*4 + q of row (== ml mod 8)
  int swz[2];
  swz[0] = ((q + ml) & 7) * 8;
  swz[1] = ((4 + q + ml) & 7) * 8;
  int arow[4], brow[4];
  #pragma unroll
  for (int i = 0; i < 4; ++i) {
    arow[i] = (wm + i * 16 + ml) * 64;
    brow[i] = (wn + i * 16 + ml) * 64;
  }

  for (int kt = 0; kt < I_SZ / 64; ++kt) {
    __syncthreads();
    #pragma unroll
    for (int jj = 0; jj < 4; ++jj) {
      GLOAD_LDS16(gA + (size_t)(jj * 8) * I_SZ + kt * 64, lA + jj * 512);
      GLOAD_LDS16(gB + (size_t)(jj * 8) * I_SZ + kt * 64, lB + jj * 512);
    }
    __syncthreads();
    #pragma unroll
    for (int ks = 0; ks < 2; ++ks) {
      bf16x8 af[4], bfr[4];
      #pragma unroll
      for (int i = 0; i < 4; ++i) {
        af[i]  = *(const bf16x8*)&As[arow[i] + swz[ks]];
        bfr[i] = *(const bf16x8*)&Bs[brow[i] + swz[ks]];
      }
      #pragma unroll
      for (int mi = 0; mi < 4; ++mi)
        #pragma unroll
        for (int ni = 0; ni < 4; ++ni)
          acc[mi][ni] = __builtin_amdgcn_mfma_f32_16x16x32_bf16(
              af[mi], bfr[ni], acc[mi][ni], 0, 0, 0);
    }
  }

  // epilogue: AGPR -> LDS (bf16, stride-136 rows) -> coalesced 16B/lane stores
  __syncthreads();
  ushort* Cs = smem;                   // 128 x 136 ushort = 34816 B
  const int rl0 = wm + q * 4;
  #pragma unroll
  for (int mi = 0; mi < 4; ++mi)
    #pragma unroll
    for (int ni = 0; ni < 4; ++ni)
      #pragma unroll
      for (int r = 0; r < 4; ++r)
        Cs[(rl0 + mi * 16 + r) * 136 + wn + ni * 16 + ml] = f2bf(acc[mi][ni][r]);
  __syncthreads();

  const size_t gbase = (size_t)(bm * 128) * H_SZ + bn * 128;
  #pragma unroll
  for (int i = 0; i < 8; ++i) {
    int chunk = i * 256 + tid;         // 0..2047
    int row = chunk >> 4, c8 = chunk & 15;
    uint4 v = *(const uint4*)&Cs[row * 136 + c8 * 8];
    *(uint4*)&U[gbase + (size_t)row * H_SZ + c8 * 8] = v;
  }
}

// ---------------------------------------------------------------- scan
// u bf16 [s][b][h]; 2 adjacent-h chains per thread via uint loads.
__global__ __launch_bounds__(256) void scan_kernel(
    const uint* __restrict__ U2, const float* __restrict__ hh,
    float* __restrict__ hstate) {
  int p = blockIdx.x * 256 + threadIdx.x;     // pair index 0..65535
  int h0 = (2 * p) & (H_SZ - 1);
  float c0 = hh[h0], c1 = hh[h0 + 1];
  float ha = 0.0f, hb = 0.0f;
  const uint* Up = U2 + p;
  for (int s0 = 0; s0 < S_LEN; s0 += 16) {
    uint v[16];
    #pragma unroll
    for (int t = 0; t < 16; ++t) v[t] = Up[(size_t)(s0 + t) * (BH / 2)];
    #pragma unroll
    for (int t = 0; t < 16; ++t) {
      float ua = __builtin_bit_cast(float, (v[t] & 0xffffu) << 16);
      float ub = __builtin_bit_cast(float, v[t] & 0xffff0000u);
      ha = fabsf(ua + c0 * ha);
      hb = fabsf(ub + c1 * hb);
    }
  }
  ((float2*)hstate)[p] = make_float2(ha, hb);
}

// ---------------------------------------------------------------- final Y = h @ W_ho^T + b
__global__ __launch_bounds__(256) void init_y_kernel(
    const float* __restrict__ bho, float* __restrict__ Y) {
  int idx = blockIdx.x * 256 + threadIdx.x;   // 0..32767
  Y[idx] = bho[idx & (O_SZ - 1)];
}

// grid (og=8, kc=16); block: 64 b x 64 o tile, thread 4x4 regs, k-range 128 (2 stages)
__global__ __launch_bounds__(256) void final_tiled_kernel(
    const float* __restrict__ hstate, const float* __restrict__ Who,
    float* __restrict__ Y) {
  __shared__ float Ws[64 * 68];
  __shared__ float Hs[64 * 68];
  const int tid = threadIdx.x;
  const int og = blockIdx.x, kc = blockIdx.y;
  const int to = tid & 15, tb = tid >> 4;     // o0 = to*4, b0 = tb*4
  float acc[4][4] = {};
  #pragma unroll
  for (int ks = 0; ks < 2; ++ks) {
    const int k0 = kc * 128 + ks * 64;
    const int r = tid >> 2, cg = (tid & 3) * 16;
    #pragma unroll
    for (int i2 = 0; i2 < 4; ++i2) {
      *(float4*)&Ws[r * 68 + cg + i2 * 4] =
          *(const float4*)&Who[(size_t)(og * 64 + r) * H_SZ + k0 + cg + i2 * 4];
      *(float4*)&Hs[r * 68 + cg + i2 * 4] =
          *(const float4*)&hstate[(size_t)r * H_SZ + k0 + cg + i2 * 4];
    }
    __syncthreads();
    #pragma unroll 4
    for (int k = 0; k < 64; ++k) {
      float wv[4], hv[4];
      #pragma unroll
      for (int jj2 = 0; jj2 < 4; ++jj2) wv[jj2] = Ws[(to * 4 + jj2) * 68 + k];
      #pragma unroll
      for (int ii = 0; ii < 4; ++ii) hv[ii] = Hs[(tb * 4 + ii) * 68 + k];
      #pragma unroll
      for (int ii = 0; ii < 4; ++ii)
        #pragma unroll
        for (int jj2 = 0; jj2 < 4; ++jj2)
          acc[ii][jj2] += hv[ii] * wv[jj2];
    }
    __syncthreads();
  }
  #pragma unroll
  for (int ii = 0; ii < 4; ++ii)
    #pragma unroll
    for (int jj2 = 0; jj2 < 4; ++jj2)
      atomicAdd(&Y[(size_t)(tb * 4 + ii) * O_SZ + og * 64 + to * 4 + jj2],
                acc[ii][jj2]);
}

// ---------------------------------------------------------------- launch
extern "C" void kernel_launch(void* const* d_in, const int* in_sizes, int n_in,
                              void* d_out, int out_size, void* d_ws, size_t ws_size,
                              hipStream_t stream) {
  (void)in_sizes; (void)n_in; (void)out_size; (void)ws_size;
  const float* X   = (const float*)d_in[0];   // [1024][64][512]
  const float* Wih = (const float*)d_in[1];   // [2048][512]
  const float* hh  = (const float*)d_in[2];   // [2048]
  const float* Who = (const float*)d_in[3];   // [512][2048]
  const float* bho = (const float*)d_in[4];   // [512]
  float* Y = (float*)d_out;                   // [64][512]

  const size_t XBF = (size_t)S_LEN * B_SZ * I_SZ * 2;  // 64 MiB
  const size_t WBF = (size_t)H_SZ * I_SZ * 2;          // 2 MiB
  const size_t HST = (size_t)BH * 4;                   // 512 KiB

  char* w = (char*)d_ws;
  ushort* Xbf    = (ushort*)w;
  ushort* Wbf    = (ushort*)(w + XBF);
  float*  hstate = (float*) (w + XBF + WBF);
  ushort* U      = (ushort*)(w + XBF + WBF + HST);     // [65536][2048] bf16, 256 MiB

  // converts
  {
    int n4x = (int)((size_t)S_LEN * B_SZ * I_SZ / 4);  // 8388608
    convert_f32_bf16_kernel<<<n4x / 256, 256, 0, stream>>>(
        (const float4*)X, (ushort4*)Xbf, n4x);
    int n4w = (int)((size_t)H_SZ * I_SZ / 4);          // 262144
    convert_f32_bf16_kernel<<<n4w / 256, 256, 0, stream>>>(
        (const float4*)Wih, (ushort4*)Wbf, n4w);
  }

  // single GEMM over all of S*B rows
  gemm_u_kernel<<<8192, 256, 0, stream>>>(Xbf, Wbf, U);

  // scan (2 chains/thread)
  scan_kernel<<<(BH / 2) / 256, 256, 0, stream>>>((const uint*)U, hh, hstate);

  // final
  init_y_kernel<<<(B_SZ * O_SZ) / 256, 256, 0, stream>>>(bho, Y);
  final_tiled_kernel<<<dim3(O_SZ / 64, 16), 256, 0, stream>>>(hstate, Who, Y);
}

// Round 3
// 414.277 us; speedup vs baseline: 1.4391x; 1.0942x over previous
//
#include <hip/hip_runtime.h>
#include <hip/hip_bf16.h>
#include <stdint.h>

// Problem constants
#define S_LEN 1024
#define B_SZ  64
#define I_SZ  512
#define H_SZ  2048
#define O_SZ  512
#define BH    (B_SZ * H_SZ)      // 131072

typedef __bf16  bf16x8 __attribute__((ext_vector_type(8)));
typedef float   f32x4  __attribute__((ext_vector_type(4)));

static __device__ __forceinline__ ushort f2bf(float f) {
  union { float f; unsigned u; } v; v.f = f;
  unsigned r = v.u + 0x7FFFu + ((v.u >> 16) & 1u);   // RNE
  return (ushort)(r >> 16);
}
static __device__ __forceinline__ float bf2f(ushort u) {
  return __builtin_bit_cast(float, (unsigned)u << 16);
}

// async global->LDS, 16B per lane, wave-uniform LDS base + lane*16
#define GLOAD_LDS16(gp, lp) \
  __builtin_amdgcn_global_load_lds( \
      (__attribute__((address_space(1))) void*)(gp), \
      (__attribute__((address_space(3))) void*)(lp), 16, 0, 0)

// ---------------------------------------------------------------- converts
__global__ __launch_bounds__(256) void convert_f32_bf16_kernel(
    const float4* __restrict__ in, ushort4* __restrict__ out, int n4) {
  int i = blockIdx.x * 256 + threadIdx.x;
  if (i >= n4) return;
  float4 v = in[i];
  ushort4 o; o.x = f2bf(v.x); o.y = f2bf(v.y); o.z = f2bf(v.z); o.w = f2bf(v.w);
  out[i] = o;
}

// ---------------------------------------------------------------- fused GEMM + scan
// Grid: 1024 blocks = (b, ht). Block computes u[s, b, ht*128 .. +128) tile-by-tile
// (8 s-tiles of 128x128, K=512) entirely in LDS and advances the diagonal
// recurrence h = |u + c*h| between tiles. u never touches HBM.
// XCD swizzle: the 16 ht-blocks of one b share an XCD (bid%8 heuristic) -> X L2-local.
// LDS: As(16K)+Bs(16K) overlapped by Cs(128x132 bf16 = 33792B). Row-stride 132
// makes epilogue writes and column-scan reads 2-way (free).
__global__ __launch_bounds__(256, 4) void fused_gemm_scan_kernel(
    const ushort* __restrict__ Xbf,   // [1024][64][512] bf16
    const ushort* __restrict__ Wbf,   // [2048][512] bf16
    const float* __restrict__ hh,     // [2048]
    float* __restrict__ hstate) {     // [64][2048]
  __shared__ __align__(16) ushort smem[16896];   // 33792 B
  ushort* As = smem;                  // 128 rows x 64 k
  ushort* Bs = smem + 8192;
  ushort* Cs = smem;                  // 128 s x 132 (reuses As+Bs space)

  const int tid  = threadIdx.x;
  const int wave = tid >> 6;
  const int lane = tid & 63;

  const int bid = blockIdx.x;
  const int x = bid & 7;              // XCD
  const int g = bid >> 3;             // 0..127
  const int b  = (x << 3) | (g & 7);  // batch 0..63
  const int ht = g >> 3;              // h-tile 0..15

  const int wm = (wave >> 1) * 64;    // s-offset within tile
  const int wn = (wave & 1) * 64;     // h-offset within tile
  const int ml = lane & 15;
  const int q  = lane >> 4;

  // staging: wave stages 32 rows of A and B; slot s of row r holds chunk (s-r)&7
  const int r0     = wave * 32;
  const int srow   = lane >> 3;
  const int schunk = ((lane & 7) - srow) & 7;
  const ushort* gA0 = Xbf + ((size_t)(r0 + srow) * B_SZ + b) * I_SZ + schunk * 8;
  const ushort* gB  = Wbf + (size_t)(ht * 128 + r0 + srow) * I_SZ + schunk * 8;
  ushort* lA = As + r0 * 64;
  ushort* lB = Bs + r0 * 64;

  int swz[2];
  swz[0] = ((q + ml) & 7) * 8;
  swz[1] = ((4 + q + ml) & 7) * 8;
  int arow[4], brow[4];
  #pragma unroll
  for (int i = 0; i < 4; ++i) {
    arow[i] = (wm + i * 16 + ml) * 64;
    brow[i] = (wn + i * 16 + ml) * 64;
  }

  float c = 0.0f, hst = 0.0f;
  if (tid < 128) c = hh[ht * 128 + tid];

  for (int st = 0; st < 8; ++st) {
    f32x4 acc[4][4] = {};
    const ushort* gA = gA0 + (size_t)st * 128 * B_SZ * I_SZ;

    for (int kt = 0; kt < I_SZ / 64; ++kt) {
      __syncthreads();   // also protects Cs readers (prev scan) from restaging
      #pragma unroll
      for (int jj = 0; jj < 4; ++jj) {
        GLOAD_LDS16(gA + (size_t)(jj * 8) * B_SZ * I_SZ + kt * 64, lA + jj * 512);
        GLOAD_LDS16(gB + (size_t)(jj * 8) * I_SZ + kt * 64, lB + jj * 512);
      }
      __syncthreads();
      #pragma unroll
      for (int ks = 0; ks < 2; ++ks) {
        bf16x8 af[4], bfr[4];
        #pragma unroll
        for (int i = 0; i < 4; ++i) {
          af[i]  = *(const bf16x8*)&As[arow[i] + swz[ks]];
          bfr[i] = *(const bf16x8*)&Bs[brow[i] + swz[ks]];
        }
        #pragma unroll
        for (int mi = 0; mi < 4; ++mi)
          #pragma unroll
          for (int ni = 0; ni < 4; ++ni)
            acc[mi][ni] = __builtin_amdgcn_mfma_f32_16x16x32_bf16(
                af[mi], bfr[ni], acc[mi][ni], 0, 0, 0);
      }
    }

    // epilogue: acc -> Cs (bf16, stride 132)
    __syncthreads();
    const int rl0 = wm + q * 4;
    #pragma unroll
    for (int mi = 0; mi < 4; ++mi)
      #pragma unroll
      for (int ni = 0; ni < 4; ++ni)
        #pragma unroll
        for (int r = 0; r < 4; ++r)
          Cs[(rl0 + mi * 16 + r) * 132 + wn + ni * 16 + ml] = f2bf(acc[mi][ni][r]);
    __syncthreads();

    // scan: 128 threads, one h-column each, 128 sequential steps
    if (tid < 128) {
      #pragma unroll
      for (int s8 = 0; s8 < 128; s8 += 8) {
        float uv[8];
        #pragma unroll
        for (int t = 0; t < 8; ++t) uv[t] = bf2f(Cs[(s8 + t) * 132 + tid]);
        #pragma unroll
        for (int t = 0; t < 8; ++t) hst = fabsf(uv[t] + c * hst);
      }
    }
  }

  if (tid < 128) hstate[(size_t)b * H_SZ + ht * 128 + tid] = hst;
}

// ---------------------------------------------------------------- final Y = h @ W_ho^T + b
__global__ __launch_bounds__(256) void init_y_kernel(
    const float* __restrict__ bho, float* __restrict__ Y) {
  int idx = blockIdx.x * 256 + threadIdx.x;   // 0..32767
  Y[idx] = bho[idx & (O_SZ - 1)];
}

// grid (og=8, kc=16); block: 64 b x 64 o tile, thread 4x4 regs, k-range 128
__global__ __launch_bounds__(256) void final_tiled_kernel(
    const float* __restrict__ hstate, const float* __restrict__ Who,
    float* __restrict__ Y) {
  __shared__ float Ws[64 * 68];
  __shared__ float Hs[64 * 68];
  const int tid = threadIdx.x;
  const int og = blockIdx.x, kc = blockIdx.y;
  const int to = tid & 15, tb = tid >> 4;     // o0 = to*4, b0 = tb*4
  float acc[4][4] = {};
  #pragma unroll
  for (int ks = 0; ks < 2; ++ks) {
    const int k0 = kc * 128 + ks * 64;
    const int r = tid >> 2, cg = (tid & 3) * 16;
    #pragma unroll
    for (int i2 = 0; i2 < 4; ++i2) {
      *(float4*)&Ws[r * 68 + cg + i2 * 4] =
          *(const float4*)&Who[(size_t)(og * 64 + r) * H_SZ + k0 + cg + i2 * 4];
      *(float4*)&Hs[r * 68 + cg + i2 * 4] =
          *(const float4*)&hstate[(size_t)r * H_SZ + k0 + cg + i2 * 4];
    }
    __syncthreads();
    #pragma unroll 4
    for (int k = 0; k < 64; ++k) {
      float wv[4], hv[4];
      #pragma unroll
      for (int jj2 = 0; jj2 < 4; ++jj2) wv[jj2] = Ws[(to * 4 + jj2) * 68 + k];
      #pragma unroll
      for (int ii = 0; ii < 4; ++ii) hv[ii] = Hs[(tb * 4 + ii) * 68 + k];
      #pragma unroll
      for (int ii = 0; ii < 4; ++ii)
        #pragma unroll
        for (int jj2 = 0; jj2 < 4; ++jj2)
          acc[ii][jj2] += hv[ii] * wv[jj2];
    }
    __syncthreads();
  }
  #pragma unroll
  for (int ii = 0; ii < 4; ++ii)
    #pragma unroll
    for (int jj2 = 0; jj2 < 4; ++jj2)
      atomicAdd(&Y[(size_t)(tb * 4 + ii) * O_SZ + og * 64 + to * 4 + jj2],
                acc[ii][jj2]);
}

// ---------------------------------------------------------------- launch
extern "C" void kernel_launch(void* const* d_in, const int* in_sizes, int n_in,
                              void* d_out, int out_size, void* d_ws, size_t ws_size,
                              hipStream_t stream) {
  (void)in_sizes; (void)n_in; (void)out_size; (void)ws_size;
  const float* X   = (const float*)d_in[0];   // [1024][64][512]
  const float* Wih = (const float*)d_in[1];   // [2048][512]
  const float* hh  = (const float*)d_in[2];   // [2048]
  const float* Who = (const float*)d_in[3];   // [512][2048]
  const float* bho = (const float*)d_in[4];   // [512]
  float* Y = (float*)d_out;                   // [64][512]

  const size_t XBF = (size_t)S_LEN * B_SZ * I_SZ * 2;  // 64 MiB
  const size_t WBF = (size_t)H_SZ * I_SZ * 2;          // 2 MiB

  char* w = (char*)d_ws;
  ushort* Xbf    = (ushort*)w;
  ushort* Wbf    = (ushort*)(w + XBF);
  float*  hstate = (float*) (w + XBF + WBF);

  // converts
  {
    int n4x = (int)((size_t)S_LEN * B_SZ * I_SZ / 4);  // 8388608
    convert_f32_bf16_kernel<<<n4x / 256, 256, 0, stream>>>(
        (const float4*)X, (ushort4*)Xbf, n4x);
    int n4w = (int)((size_t)H_SZ * I_SZ / 4);          // 262144
    convert_f32_bf16_kernel<<<n4w / 256, 256, 0, stream>>>(
        (const float4*)Wih, (ushort4*)Wbf, n4w);
  }

  // fused GEMM + scan (u stays in LDS)
  fused_gemm_scan_kernel<<<1024, 256, 0, stream>>>(Xbf, Wbf, hh, hstate);

  // final
  init_y_kernel<<<(B_SZ * O_SZ) / 256, 256, 0, stream>>>(bho, Y);
  final_tiled_kernel<<<dim3(O_SZ / 64, 16), 256, 0, stream>>>(hstate, Who, Y);
}